// Round 1
// baseline (69.091 us; speedup 1.0000x reference)
//
#include <hip/hip_runtime.h>
#include <hip/hip_bf16.h>

// B=1024, D=512, K=256, NC=1.
// out[b,k] = sum_d (x-m)^2 * 0.5*softplus(rho)^2
//          = sum_d w*x^2 + a2*x + c[k],  w=0.5*sp^2, a2=-2*w*m, c=sum_d w*m^2
// Fully fused single dispatch (R5): the prep->GEMM global staging + second
// launch was pure overhead (~7 us of the 68.6 us timed region; the rest is
// harness reset: 41 us 256MB ws poison fill @ 81% HBM peak + ~20 us of tiny
// restore dispatches). Each block stages X'=[x^2,x] (16x1024 bf16, 32 KB,
// XOR-swizzled) in LDS for its b-tile; each wave computes its W' MFMA
// B-fragment in registers (softplus via __logf/__expf; bf16 rounding of w
// absorbs the ~1e-6 approximation error). c[k] via 2-step shfl_xor over the
// quad partition of d. No workspace use at all.

#define BB 1024
#define DD 512
#define KK 256

typedef __attribute__((ext_vector_type(8))) short bf16x8;
typedef __attribute__((ext_vector_type(4))) float f32x4;
typedef __attribute__((ext_vector_type(4))) unsigned short us4;

static __device__ inline unsigned short f2bf(float f) {
    __hip_bfloat16 h = __float2bfloat16(f);
    return *reinterpret_cast<unsigned short*>(&h);
}

// byte offset of bf16 column `col` in row `r` of the swizzled 16x1024 LDS tile.
// XOR of bits 4..6 with (r&7): 16-lane column reads land on 8 distinct 16B
// slots -> 2-way bank aliasing (free) instead of 16-way.
static __device__ inline int swz(int r, int col) {
    return r * 2048 + ((col * 2) ^ ((r & 7) << 4));
}

__global__ __launch_bounds__(256) void fused_kernel(const float* __restrict__ x,
                                                    const float* __restrict__ means,
                                                    const float* __restrict__ rho,
                                                    float* __restrict__ out) {
    __shared__ char Xs[32768];   // X' tile: 16 rows x 1024 bf16 (sq | lin)

    const int t  = threadIdx.x;
    const int bb = blockIdx.x >> 2;   // 4 consecutive blocks share one b-tile (L2 locality)
    const int b0 = bb * 16;

    // ---- phase 1: cooperative X' staging for this block's 16 b-rows ----
    {
        const int r = t >> 4;         // 0..15 row
        const int l = t & 15;         // 16 threads per row
        const float4* xrow = (const float4*)(x + (size_t)(b0 + r) * DD);
#pragma unroll
        for (int i = 0; i < 8; i++) {
            const float4 v = xrow[l + 16 * i];     // wave: 256B contiguous per row-group
            const int c = (l + 16 * i) * 4;        // bf16 col of this chunk
            us4 sq, ln;
            sq.x = f2bf(v.x * v.x); sq.y = f2bf(v.y * v.y);
            sq.z = f2bf(v.z * v.z); sq.w = f2bf(v.w * v.w);
            ln.x = f2bf(v.x); ln.y = f2bf(v.y); ln.z = f2bf(v.z); ln.w = f2bf(v.w);
            *(us4*)(Xs + swz(r, c))      = sq;
            *(us4*)(Xs + swz(r, DD + c)) = ln;
        }
    }
    __syncthreads();

    // ---- phase 2: one 16x16 output tile per wave; W' fragment built in regs ----
    const int lane = t & 63;
    const int wave = t >> 6;
    const int kb   = (blockIdx.x & 3) * 4 + wave;  // 0..15
    const int k0   = kb * 16;
    const int rc   = lane & 15;
    const int quad = lane >> 4;

    // lane (rc,quad) consumes W'[k0+rc][quad*8 + 32j .. +8] -> load exactly
    // those means/rho values and synthesize w / a2 in place.
    const float4* mBase = (const float4*)(means + (size_t)(k0 + rc) * DD) + quad * 2;
    const float4* rBase = (const float4*)(rho   + (size_t)(k0 + rc) * DD) + quad * 2;

    f32x4 acc = {0.f, 0.f, 0.f, 0.f};
    float csum = 0.f;

#pragma unroll 4
    for (int j = 0; j < 16; j++) {
        const float4 m0 = mBase[8 * j];
        const float4 m1 = mBase[8 * j + 1];
        const float4 r0 = rBase[8 * j];
        const float4 r1 = rBase[8 * j + 1];

        const float mm[8] = {m0.x, m0.y, m0.z, m0.w, m1.x, m1.y, m1.z, m1.w};
        const float rr[8] = {r0.x, r0.y, r0.z, r0.w, r1.x, r1.y, r1.z, r1.w};
        bf16x8 wq, aq;
#pragma unroll
        for (int e = 0; e < 8; e++) {
            const float sp = __logf(1.f + __expf(rr[e]));   // softplus, fast path
            const float wv = 0.5f * sp * sp;
            wq[e] = (short)f2bf(wv);
            aq[e] = (short)f2bf(-2.f * wv * mm[e]);
            csum += wv * mm[e] * mm[e];                     // f32 c-term (pre-round w)
        }

        const bf16x8 a_sq = *(const bf16x8*)(Xs + swz(rc, quad * 8 + 32 * j));
        const bf16x8 a_ln = *(const bf16x8*)(Xs + swz(rc, DD + quad * 8 + 32 * j));
        acc = __builtin_amdgcn_mfma_f32_16x16x32_bf16(a_sq, wq, acc, 0, 0, 0);
        acc = __builtin_amdgcn_mfma_f32_16x16x32_bf16(a_ln, aq, acc, 0, 0, 0);
    }

    // c[k0+rc]: each quad holds a disjoint quarter of the d-range -> butterfly
    csum += __shfl_xor(csum, 16);
    csum += __shfl_xor(csum, 32);

#pragma unroll
    for (int r = 0; r < 4; r++) {
        out[(size_t)(b0 + quad * 4 + r) * KK + (k0 + rc)] = acc[r] + csum;
    }
}

extern "C" void kernel_launch(void* const* d_in, const int* in_sizes, int n_in,
                              void* d_out, int out_size, void* d_ws, size_t ws_size,
                              hipStream_t stream) {
    const float* x     = (const float*)d_in[0];
    const float* means = (const float*)d_in[1];
    const float* rho   = (const float*)d_in[2];
    float* out = (float*)d_out;
    (void)d_ws; (void)ws_size;

    fused_kernel<<<256, 256, 0, stream>>>(x, means, rho, out);
}